// Round 1
// baseline (332.602 us; speedup 1.0000x reference)
//
#include <hip/hip_runtime.h>
#include <hip/hip_bf16.h>
#include <cstdint>

// ---------------------------------------------------------------------------
// DynamicRouting: hat = enc @ W^T  (fp16 MFMA, fp32 accum), then 3 routing
// iterations fused in one kernel (hat held in registers per capsule block).
// enc: [C=512, K=64, H=1024] fp32;  W: [1024,1024] fp32;  out c: [512,1024] fp32
// ---------------------------------------------------------------------------

#define C_DIM 512
#define KCAPS 64
#define H_DIM 1024
#define M_DIM (C_DIM * KCAPS)   // 32768

typedef _Float16 h8 __attribute__((ext_vector_type(8)));
typedef _Float16 h4 __attribute__((ext_vector_type(4)));
typedef float f4 __attribute__((ext_vector_type(4)));

// ---------------- convert fp32 -> fp16 (vectorized) ----------------
__global__ void cvt_f32_f16(const float* __restrict__ in, _Float16* __restrict__ out, int n4) {
    int i = blockIdx.x * blockDim.x + threadIdx.x;
    int stride = gridDim.x * blockDim.x;
    for (; i < n4; i += stride) {
        float4 v = ((const float4*)in)[i];
        h4 o;
        o[0] = (_Float16)v.x; o[1] = (_Float16)v.y;
        o[2] = (_Float16)v.z; o[3] = (_Float16)v.w;
        ((h4*)out)[i] = o;
    }
}

// ---------------- GEMM: hat[m,o] = sum_h A[m,h] * B[o,h] ----------------
// m97-style 128x128 tile, BK=64, 4 waves, global_load_lds width 16.
__device__ __forceinline__ void gload16(const _Float16* g, _Float16* l) {
    __builtin_amdgcn_global_load_lds(
        (const __attribute__((address_space(1))) void*)g,
        (__attribute__((address_space(3))) void*)l, 16, 0, 0);
}

__global__ __launch_bounds__(256) void gemm_f16_bt(const _Float16* __restrict__ A,
                                                   const _Float16* __restrict__ B,
                                                   _Float16* __restrict__ Cmat) {
    __shared__ _Float16 As[128 * 64] __attribute__((aligned(16)));
    __shared__ _Float16 Bs[128 * 64] __attribute__((aligned(16)));
    const int tid  = threadIdx.x;
    const int lane = tid & 63;
    const int wid  = tid >> 6;           // 4 waves
    const int tm   = blockIdx.x >> 3;    // 256 row tiles
    const int tn   = blockIdx.x & 7;     // 8 col tiles
    const int wr   = wid >> 1, wc = wid & 1;

    f4 acc[4][4] = {};

    const int r8 = lane >> 3;            // row within 8-row chunk
    const int c8 = (lane & 7) * 8;       // half-index col within 64

    const _Float16* Abase = A + (size_t)(tm * 128) * H_DIM;
    const _Float16* Bbase = B + (size_t)(tn * 128) * H_DIM;

    for (int kt = 0; kt < H_DIM; kt += 64) {
        // stage A,B tiles: each wave issues 4+4 global_load_lds (1 KB each)
        #pragma unroll
        for (int i = 0; i < 4; ++i) {
            const int chunk = wid * 4 + i;       // 0..15, 8 rows each
            const int row   = chunk * 8 + r8;
            gload16(Abase + (size_t)row * H_DIM + kt + c8, &As[chunk * 512]);
            gload16(Bbase + (size_t)row * H_DIM + kt + c8, &Bs[chunk * 512]);
        }
        __syncthreads();   // compiler emits vmcnt(0) drain before barrier

        #pragma unroll
        for (int kk = 0; kk < 64; kk += 32) {
            h8 af[4], bf[4];
            const int kidx = kk + ((lane >> 4) << 3);
            #pragma unroll
            for (int m = 0; m < 4; ++m)
                af[m] = *(const h8*)&As[(wr * 64 + m * 16 + (lane & 15)) * 64 + kidx];
            #pragma unroll
            for (int n = 0; n < 4; ++n)
                bf[n] = *(const h8*)&Bs[(wc * 64 + n * 16 + (lane & 15)) * 64 + kidx];
            #pragma unroll
            for (int m = 0; m < 4; ++m)
                #pragma unroll
                for (int n = 0; n < 4; ++n)
                    acc[m][n] = __builtin_amdgcn_mfma_f32_16x16x32_f16(af[m], bf[n], acc[m][n], 0, 0, 0);
        }
        __syncthreads();
    }

    // epilogue: C/D layout col=lane&15, row=(lane>>4)*4+q (m89-verified family)
    const int crow0 = tm * 128 + wr * 64;
    const int ccol0 = tn * 128 + wc * 64;
    #pragma unroll
    for (int m = 0; m < 4; ++m) {
        #pragma unroll
        for (int n = 0; n < 4; ++n) {
            const int col = ccol0 + n * 16 + (lane & 15);
            #pragma unroll
            for (int q = 0; q < 4; ++q) {
                const int row = crow0 + m * 16 + (lane >> 4) * 4 + q;
                Cmat[(size_t)row * H_DIM + col] = (_Float16)acc[m][n][q];
            }
        }
    }
}

// ---------------- fused routing: 3 iterations, hat in registers ----------------
__device__ __forceinline__ float2 upk(unsigned int u) {
    unsigned short ul = (unsigned short)(u & 0xffffu);
    unsigned short uh = (unsigned short)(u >> 16);
    _Float16 lo, hi;
    __builtin_memcpy(&lo, &ul, 2);
    __builtin_memcpy(&hi, &uh, 2);
    return make_float2((float)lo, (float)hi);
}

__global__ __launch_bounds__(512) void routing_kernel(const _Float16* __restrict__ hat,
                                                      float* __restrict__ out) {
    const int c    = blockIdx.x;      // capsule row 0..511
    const int t    = threadIdx.x;     // owns h = 2t, 2t+1
    const int lane = t & 63;
    const int wid  = t >> 6;          // 8 waves

    __shared__ float b_lds[64];
    __shared__ float d_lds[64];
    __shared__ float red[8];
    __shared__ float bpart[8][64];
    __shared__ float norm_sh;

    // load hat[c,k,2t..2t+1] packed (one uint per k) — 64 VGPRs
    unsigned int hp[64];
    const unsigned int* base = (const unsigned int*)(hat + (size_t)c * KCAPS * H_DIM) + t;
    #pragma unroll
    for (int k = 0; k < 64; ++k) hp[k] = base[k * (H_DIM / 2)];

    if (t < 64) b_lds[t] = 0.0f;
    __syncthreads();

    float cx = 0.0f, cy = 0.0f;

    for (int it = 0; it < 3; ++it) {
        // softmax over K=64 by wave 0
        if (t < 64) {
            float bv = b_lds[t];
            float mx = bv;
            #pragma unroll
            for (int s = 1; s < 64; s <<= 1) mx = fmaxf(mx, __shfl_xor(mx, s, 64));
            float e = __expf(bv - mx);
            float sum = e;
            #pragma unroll
            for (int s = 1; s < 64; s <<= 1) sum += __shfl_xor(sum, s, 64);
            d_lds[t] = e / sum;
        }
        __syncthreads();

        // c_hat = sum_k hat[k] * d[k]
        float chx = 0.0f, chy = 0.0f;
        #pragma unroll
        for (int k = 0; k < 64; ++k) {
            float2 f = upk(hp[k]);
            float dk = d_lds[k];
            chx = fmaf(f.x, dk, chx);
            chy = fmaf(f.y, dk, chy);
        }

        // norm^2 over H: wave reduce + cross-wave
        float nn = chx * chx + chy * chy;
        #pragma unroll
        for (int s = 1; s < 64; s <<= 1) nn += __shfl_xor(nn, s, 64);
        if (lane == 0) red[wid] = nn;
        __syncthreads();
        if (t == 0) {
            float tot = 0.0f;
            #pragma unroll
            for (int w = 0; w < 8; ++w) tot += red[w];
            norm_sh = tot;
        }
        __syncthreads();
        const float ns = norm_sh;
        const float scale = (ns / (1.0f + ns)) / sqrtf(ns + 1e-9f);
        cx = chx * scale;
        cy = chy * scale;

        if (it < 2) {
            // b[k] += sum_h hat[k,h]*c[h] : in-wave 64x64 butterfly transpose-reduce
            float v[32];
            // stage 0 fused with product computation (keeps live regs low)
            #pragma unroll
            for (int i = 0; i < 32; ++i) {
                float2 fa = upk(hp[2 * i]);
                float2 fb = upk(hp[2 * i + 1]);
                float pa = fmaf(fa.x, cx, fa.y * cy);
                float pb = fmaf(fb.x, cx, fb.y * cy);
                const bool hi = (lane & 1) != 0;
                float keep = hi ? pb : pa;
                float send = hi ? pa : pb;
                v[i] = keep + __shfl_xor(send, 1, 64);
            }
            #pragma unroll
            for (int bit = 1; bit < 6; ++bit) {
                const int s = 1 << bit;
                const int n = 64 >> (bit + 1);
                const bool hi = (lane & s) != 0;
                #pragma unroll
                for (int i = 0; i < n; ++i) {
                    float keep = hi ? v[2 * i + 1] : v[2 * i];
                    float send = hi ? v[2 * i] : v[2 * i + 1];
                    v[i] = keep + __shfl_xor(send, s, 64);
                }
            }
            // lane l now holds this wave's partial for k = l
            bpart[wid][lane] = v[0];
            __syncthreads();
            if (t < 64) {
                float s = 0.0f;
                #pragma unroll
                for (int w = 0; w < 8; ++w) s += bpart[w][t];
                b_lds[t] += s;
            }
            __syncthreads();
        }
    }

    float2 o;
    o.x = cx; o.y = cy;
    *(float2*)&out[(size_t)c * H_DIM + 2 * t] = o;
}

// ---------------------------------------------------------------------------
extern "C" void kernel_launch(void* const* d_in, const int* in_sizes, int n_in,
                              void* d_out, int out_size, void* d_ws, size_t ws_size,
                              hipStream_t stream) {
    const float* enc = (const float*)d_in[0];   // [512,64,1024] fp32
    const float* Wf  = (const float*)d_in[1];   // [1024,1024] fp32
    float* out = (float*)d_out;                 // [512,1024] fp32

    char* ws = (char*)d_ws;
    _Float16* enc16 = (_Float16*)ws;                                   // 64 MB
    _Float16* W16   = (_Float16*)(ws + (size_t)67108864);              //  2 MB
    _Float16* hat16 = (_Float16*)(ws + (size_t)67108864 + 2097152);    // 64 MB

    const int n_enc = C_DIM * KCAPS * H_DIM;   // 33554432
    const int n_w   = H_DIM * H_DIM;           // 1048576

    cvt_f32_f16<<<2048, 256, 0, stream>>>(enc, enc16, n_enc / 4);
    cvt_f32_f16<<<512, 256, 0, stream>>>(Wf, W16, n_w / 4);

    gemm_f16_bt<<<(M_DIM / 128) * (H_DIM / 128), 256, 0, stream>>>(enc16, W16, hat16);

    routing_kernel<<<C_DIM, 512, 0, stream>>>(hat16, out);
}